// Round 1
// baseline (815.708 us; speedup 1.0000x reference)
//
#include <hip/hip_runtime.h>

#define N_ROWS 131072
#define DIM 64
#define KCODES 1024
#define KT 128  // k-tile staged in LDS: 128*64*4 = 32 KiB

// Transpose embeddings [D][K] -> et [K][D] and compute h2[k] = 0.5*||e_k||^2.
__global__ __launch_bounds__(256) void vq_prep(const float* __restrict__ emb,
                                               float* __restrict__ et,
                                               float* __restrict__ h2) {
  int k = blockIdx.x * blockDim.x + threadIdx.x;  // 0..1023, coalesced over k
  float s = 0.f;
#pragma unroll
  for (int d = 0; d < DIM; ++d) {
    float v = emb[d * KCODES + k];
    et[k * DIM + d] = v;
    s = fmaf(v, v, s);
  }
  h2[k] = 0.5f * s;
}

// One thread per row. f-row in registers; e_k broadcast from LDS tile.
__global__ __launch_bounds__(256) void vq_main(const float* __restrict__ x,
                                               const float* __restrict__ et,
                                               const float* __restrict__ h2,
                                               float* __restrict__ out) {
  __shared__ float lds_e[KT * DIM];
  __shared__ float lds_h[KT];

  const int row = blockIdx.x * blockDim.x + threadIdx.x;

  // Load this thread's row into registers (16 x float4 = 64 floats).
  float4 f[16];
  const float4* xr = (const float4*)(x + (size_t)row * DIM);
#pragma unroll
  for (int i = 0; i < 16; ++i) f[i] = xr[i];

  float best = 3.4e38f;
  int bi = 0;

  for (int kt = 0; kt < KCODES; kt += KT) {
    __syncthreads();  // protect LDS from previous tile's readers
    {
      // Cooperative coalesced load of the k-tile: 128*64 floats = 2048 float4,
      // 256 threads -> 8 float4 each.
      const float4* src = (const float4*)(et + (size_t)kt * DIM);
      float4* dst = (float4*)lds_e;
#pragma unroll
      for (int i = 0; i < (KT * DIM / 4) / 256; ++i)
        dst[threadIdx.x + i * 256] = src[threadIdx.x + i * 256];
      if (threadIdx.x < KT) lds_h[threadIdx.x] = h2[kt + threadIdx.x];
    }
    __syncthreads();

#pragma unroll 2
    for (int kk = 0; kk < KT; ++kk) {
      const float4* e = (const float4*)(lds_e + kk * DIM);  // same addr all lanes -> LDS broadcast
      float a0 = 0.f, a1 = 0.f, a2 = 0.f, a3 = 0.f;
#pragma unroll
      for (int i = 0; i < 16; ++i) {
        float4 ev = e[i];
        a0 = fmaf(f[i].x, ev.x, a0);
        a1 = fmaf(f[i].y, ev.y, a1);
        a2 = fmaf(f[i].z, ev.z, a2);
        a3 = fmaf(f[i].w, ev.w, a3);
      }
      float dot = (a0 + a1) + (a2 + a3);
      float val = lds_h[kk] - dot;  // 0.5*||e||^2 - f.e  (monotone in true distance)
      if (val < best) { best = val; bi = kt + kk; }  // strict < keeps first index (argmin tie rule)
    }
  }

  // Gather winning codebook row and store (coalesced per-row float4s).
  const float4* q = (const float4*)(et + (size_t)bi * DIM);
  float4* o = (float4*)(out + (size_t)row * DIM);
#pragma unroll
  for (int i = 0; i < 16; ++i) o[i] = q[i];
}

extern "C" void kernel_launch(void* const* d_in, const int* in_sizes, int n_in,
                              void* d_out, int out_size, void* d_ws, size_t ws_size,
                              hipStream_t stream) {
  const float* x = (const float*)d_in[0];
  const float* emb = (const float*)d_in[1];
  float* out = (float*)d_out;

  float* et = (float*)d_ws;            // 1024*64 floats = 256 KiB
  float* h2 = et + KCODES * DIM;       // 1024 floats

  vq_prep<<<KCODES / 256, 256, 0, stream>>>(emb, et, h2);
  vq_main<<<N_ROWS / 256, 256, 0, stream>>>(x, et, h2, out);
}